// Round 1
// baseline (232.737 us; speedup 1.0000x reference)
//
#include <hip/hip_runtime.h>

#define NUM_CLASS 1000
#define DIMS 2048
#define NHEADS 8
#define HEAD (DIMS / NHEADS)     // 256
#define NBATCH 16384
#define ALPHA 0.999f

// loss scale: 1 / (N * HEAD) = 1 / 2^22 (exact)
#define LOSS_SCALE (1.0f / (16384.0f * 256.0f))

__device__ __forceinline__ float wave_reduce_sum(float v) {
    #pragma unroll
    for (int off = 32; off > 0; off >>= 1)
        v += __shfl_down(v, off, 64);
    return v;
}

// Kernel 1: per-class last occurrence (last-write-wins semantics)
__global__ void last_idx_kernel(const int* __restrict__ labels, int* __restrict__ last) {
    int i = blockIdx.x * blockDim.x + threadIdx.x;
    if (i < NBATCH) {
        atomicMax(&last[labels[i]], i);
    }
}

// Kernel 2: MSE loss, vectorized float4, grid-stride, block-reduced atomicAdd
__global__ void loss_kernel(const float* __restrict__ x,
                            const int* __restrict__ labels,
                            const float* __restrict__ centers,
                            float* __restrict__ out_loss) {
    const int total4 = NBATCH * (DIMS / 4);   // 8,388,608 float4 elements
    const int row4 = DIMS / 4;                // 512 (power of 2)

    float acc = 0.0f;
    for (int i = blockIdx.x * blockDim.x + threadIdx.x; i < total4;
         i += gridDim.x * blockDim.x) {
        int row  = i >> 9;          // i / 512
        int col4 = i & (row4 - 1);  // i % 512
        int lbl  = labels[row];
        float4 xv = reinterpret_cast<const float4*>(x)[i];
        float4 cv = reinterpret_cast<const float4*>(centers)[lbl * row4 + col4];
        float dx = xv.x - cv.x;
        float dy = xv.y - cv.y;
        float dz = xv.z - cv.z;
        float dw = xv.w - cv.w;
        acc += dx * dx + dy * dy + dz * dz + dw * dw;
    }

    // block reduction: wave shfl -> LDS -> single atomic per block
    __shared__ float sm[4];  // 256 threads = 4 waves
    int lane = threadIdx.x & 63;
    int wid  = threadIdx.x >> 6;
    acc = wave_reduce_sum(acc);
    if (lane == 0) sm[wid] = acc;
    __syncthreads();
    if (wid == 0) {
        float v = (lane < 4) ? sm[lane] : 0.0f;
        v = wave_reduce_sum(v);
        if (lane == 0) atomicAdd(out_loss, v * LOSS_SCALE);
    }
}

// Kernel 3: EMA scatter update into new_centers (d_out + 1 float, 4B-aligned)
__global__ void update_kernel(const float* __restrict__ x,
                              const float* __restrict__ centers,
                              const int* __restrict__ last,
                              float* __restrict__ newc) {
    int i = blockIdx.x * blockDim.x + threadIdx.x;  // over NUM_CLASS*DIMS
    if (i >= NUM_CLASS * DIMS) return;
    int k = i >> 11;          // i / 2048
    int d = i & (DIMS - 1);   // i % 2048
    float c = centers[i];
    int li = last[k];
    float v = c;
    if (li >= 0) {
        float xv = x[li * DIMS + d];
        v = ALPHA * c + (1.0f - ALPHA) * xv;
    }
    newc[i] = v;
}

extern "C" void kernel_launch(void* const* d_in, const int* in_sizes, int n_in,
                              void* d_out, int out_size, void* d_ws, size_t ws_size,
                              hipStream_t stream) {
    const float* x       = (const float*)d_in[0];
    const int*   labels  = (const int*)d_in[1];
    const float* centers = (const float*)d_in[2];

    float* out_loss = (float*)d_out;          // d_out[0] = loss
    float* out_newc = (float*)d_out + 1;      // d_out[1..] = new_centers flat

    int* last = (int*)d_ws;                   // NUM_CLASS ints

    // init: last = -1 (0xFF bytes), loss accumulator = 0
    hipMemsetAsync(last, 0xFF, NUM_CLASS * sizeof(int), stream);
    hipMemsetAsync(out_loss, 0, sizeof(float), stream);

    // 1) last occurrence per class
    last_idx_kernel<<<(NBATCH + 255) / 256, 256, 0, stream>>>(labels, last);

    // 2) loss (independent of kernel 1; stream-ordered anyway)
    loss_kernel<<<2048, 256, 0, stream>>>(x, labels, centers, out_loss);

    // 3) EMA update (depends on kernel 1; stream order guarantees it)
    update_kernel<<<(NUM_CLASS * DIMS + 255) / 256, 256, 0, stream>>>(
        x, centers, last, out_newc);
}

// Round 2
// 215.329 us; speedup vs baseline: 1.0808x; 1.0808x over previous
//
#include <hip/hip_runtime.h>

#define NUM_CLASS 1000
#define DIMS 2048
#define NBATCH 16384
#define ALPHA 0.999f
// loss scale: 1 / (N * HEAD) = 1 / (16384 * 256) (exact power of 2)
#define LOSS_SCALE (1.0f / (16384.0f * 256.0f))

#define BLOCK 256
#define LOSS_BLOCKS 3096
#define TOTAL_BLOCKS (NUM_CLASS + LOSS_BLOCKS)  // 4096 blocks = 16/CU

__global__ __launch_bounds__(BLOCK) void fused_kernel(
    const float* __restrict__ x,
    const int* __restrict__ labels,
    const float* __restrict__ centers,
    float* __restrict__ out_loss,
    float* __restrict__ newc) {
    __shared__ float smf[4];
    __shared__ int smi[4];
    const int tid  = threadIdx.x;
    const int lane = tid & 63;
    const int wid  = tid >> 6;
    const int b    = blockIdx.x;

    if (b < NUM_CLASS) {
        // ---- phase A: last occurrence of class b in labels ----
        int best = -1;
        for (int i = tid; i < NBATCH; i += BLOCK) {
            // i strictly increases per thread, so plain assignment keeps the max
            if (labels[i] == b) best = i;
        }
        #pragma unroll
        for (int off = 32; off > 0; off >>= 1) {
            int o = __shfl_down(best, off, 64);
            best = best > o ? best : o;
        }
        if (lane == 0) smi[wid] = best;
        __syncthreads();
        if (tid == 0) {
            int v01 = smi[0] > smi[1] ? smi[0] : smi[1];
            int v23 = smi[2] > smi[3] ? smi[2] : smi[3];
            smi[0] = v01 > v23 ? v01 : v23;
        }
        __syncthreads();
        const int li = smi[0];

        // ---- phase B: EMA update of centers row b ----
        const float4* crow = reinterpret_cast<const float4*>(centers + (size_t)b * DIMS);
        float* orow = newc + (size_t)b * DIMS;  // 4B-aligned only -> scalar stores
        if (li >= 0) {
            const float4* xrow = reinterpret_cast<const float4*>(x + (size_t)li * DIMS);
            #pragma unroll
            for (int j = 0; j < DIMS / 4 / BLOCK; ++j) {  // 2 iterations
                int e = j * BLOCK + tid;
                float4 c4 = crow[e];
                float4 x4 = xrow[e];
                float* o = orow + e * 4;
                o[0] = ALPHA * c4.x + (1.0f - ALPHA) * x4.x;
                o[1] = ALPHA * c4.y + (1.0f - ALPHA) * x4.y;
                o[2] = ALPHA * c4.z + (1.0f - ALPHA) * x4.z;
                o[3] = ALPHA * c4.w + (1.0f - ALPHA) * x4.w;
            }
        } else {
            #pragma unroll
            for (int j = 0; j < DIMS / 4 / BLOCK; ++j) {
                int e = j * BLOCK + tid;
                float4 c4 = crow[e];
                float* o = orow + e * 4;
                o[0] = c4.x; o[1] = c4.y; o[2] = c4.z; o[3] = c4.w;
            }
        }
    } else {
        // ---- loss blocks: rows strided by LOSS_BLOCKS ----
        const int lb = b - NUM_CLASS;
        float acc = 0.0f;
        for (int row = lb; row < NBATCH; row += LOSS_BLOCKS) {
            const int label = labels[row];  // wave-uniform broadcast (L1 hit)
            const float4* xr = reinterpret_cast<const float4*>(x + (size_t)row * DIMS);
            const float4* cr = reinterpret_cast<const float4*>(centers + (size_t)label * DIMS);
            #pragma unroll
            for (int j = 0; j < DIMS / 4 / BLOCK; ++j) {  // 2 iterations
                int e = j * BLOCK + tid;
                float4 xv = xr[e];
                float4 cv = cr[e];
                float dx = xv.x - cv.x;
                float dy = xv.y - cv.y;
                float dz = xv.z - cv.z;
                float dw = xv.w - cv.w;
                acc += dx * dx + dy * dy + dz * dz + dw * dw;
            }
        }
        #pragma unroll
        for (int off = 32; off > 0; off >>= 1)
            acc += __shfl_down(acc, off, 64);
        if (lane == 0) smf[wid] = acc;
        __syncthreads();
        if (tid == 0) {
            float v = (smf[0] + smf[1]) + (smf[2] + smf[3]);
            atomicAdd(out_loss, v * LOSS_SCALE);
        }
    }
}

extern "C" void kernel_launch(void* const* d_in, const int* in_sizes, int n_in,
                              void* d_out, int out_size, void* d_ws, size_t ws_size,
                              hipStream_t stream) {
    const float* x       = (const float*)d_in[0];
    const int*   labels  = (const int*)d_in[1];
    const float* centers = (const float*)d_in[2];

    float* out_loss = (float*)d_out;      // d_out[0] = loss
    float* out_newc = (float*)d_out + 1;  // d_out[1..] = new_centers flat

    hipMemsetAsync(out_loss, 0, sizeof(float), stream);
    fused_kernel<<<TOTAL_BLOCKS, BLOCK, 0, stream>>>(x, labels, centers,
                                                     out_loss, out_newc);
}